// Round 10
// baseline (127.397 us; speedup 1.0000x reference)
//
#include <hip/hip_runtime.h>
#include <hip/hip_bf16.h>

#define B_    32
#define N_    10000
#define G_    256
#define HID_  256
#define EPS_  1e-5f
#define TILE_ 256              // genes staged per LDS tile
#define WIN_  16               // W-load pipeline window (per wave)

// prep_k grid segmentation
#define TB_W1  2504            // 313 col-tiles x 8 row-tiles (W1: 256 x 10000)
#define TB_X   313             // x: 32 x 10000
#define TB_W2  64              // W2: 256 x 256
#define NB_CMP 256             // mask compaction, one block per g
#define PREP_GRID (TB_W1 + TB_X + TB_W2 + NB_CMP)   // 3137

#define DKB_  40               // dense-group split-K producer blocks
#define DCH_  250              // genes per dense chunk (40*250 = 10000)
#define MEGA_GRID (DKB_ + 255 + 1)   // 296

// ---------------------------------------------------------------------------
// Tiled transpose helpers: src R x C row-major -> dst C x R row-major.
// ---------------------------------------------------------------------------
__device__ inline void transpose_tile(const float* __restrict__ src,
                                      float* __restrict__ dst,
                                      int R, int C, int bx, int by, int t,
                                      float (*tile)[33]) {
    int tx = t & 31, ty = t >> 5;      // 32 x 8
    int c0 = bx * 32, r0 = by * 32;
#pragma unroll
    for (int j = 0; j < 4; ++j) {
        int r = r0 + ty + j * 8, c = c0 + tx;
        if (r < R && c < C) tile[ty + j * 8][tx] = src[(size_t)r * C + c];
    }
    __syncthreads();
#pragma unroll
    for (int j = 0; j < 4; ++j) {
        int c = c0 + ty + j * 8, r = r0 + tx;
        if (r < R && c < C) dst[(size_t)c * R + r] = tile[tx][ty + j * 8];
    }
}

__device__ inline void transpose_tile_bf16(const float* __restrict__ src,
                                           __hip_bfloat16* __restrict__ dst,
                                           int R, int C, int bx, int by, int t,
                                           float (*tile)[33]) {
    int tx = t & 31, ty = t >> 5;      // 32 x 8
    int c0 = bx * 32, r0 = by * 32;
#pragma unroll
    for (int j = 0; j < 4; ++j) {
        int r = r0 + ty + j * 8, c = c0 + tx;
        if (r < R && c < C) tile[ty + j * 8][tx] = src[(size_t)r * C + c];
    }
    __syncthreads();
#pragma unroll
    for (int j = 0; j < 4; ++j) {
        int c = c0 + ty + j * 8, r = r0 + tx;
        if (r < R && c < C)
            dst[(size_t)c * R + r] = __float2bfloat16(tile[tx][ty + j * 8]);
    }
}

// ---------------------------------------------------------------------------
// Fused prep: W1(bf16)/x/W2 transposes + mask compaction + ctr reset.
// ---------------------------------------------------------------------------
__global__ __launch_bounds__(256) void prep_k(const float* __restrict__ W1,
                                              const float* __restrict__ x,
                                              const float* __restrict__ W2,
                                              const float* __restrict__ mask,
                                              __hip_bfloat16* __restrict__ w1bf,
                                              float* __restrict__ xt,
                                              float* __restrict__ w2t,
                                              int* __restrict__ cnt,
                                              unsigned short* __restrict__ idx,
                                              int* __restrict__ ctr) {
    __shared__ float tile[32][33];
    __shared__ int c;
    int bid = blockIdx.x, t = threadIdx.x;

    if (bid == 0 && t == 0) *ctr = 0;  // reset mega_k producer counter

    if (bid < TB_W1) {
        transpose_tile_bf16(W1, w1bf, HID_, N_, bid % 313, bid / 313, t, tile);
    } else if (bid < TB_W1 + TB_X) {
        transpose_tile(x, xt, B_, N_, bid - TB_W1, 0, t, tile);
    } else if (bid < TB_W1 + TB_X + TB_W2) {
        int b = bid - (TB_W1 + TB_X);
        transpose_tile(W2, w2t, 256, HID_, b % 8, b / 8, t, tile);
    } else {
        int g = bid - (TB_W1 + TB_X + TB_W2);
        if (t == 0) c = 0;
        __syncthreads();
        for (int n = t; n < N_; n += 256) {
            if (mask[(size_t)g * N_ + n] != 0.0f) {
                int p = atomicAdd(&c, 1);          // LDS atomic only
                idx[(size_t)g * N_ + p] = (unsigned short)n;
            }
        }
        __syncthreads();
        if (t == 0) cnt[g] = c;
    }
}

// ---------------------------------------------------------------------------
// helpers
// ---------------------------------------------------------------------------
__device__ __forceinline__ float4 bf2f4(uint2 u) {
    float4 w;
    w.x = __uint_as_float(u.x << 16);
    w.y = __uint_as_float(u.x & 0xffff0000u);
    w.z = __uint_as_float(u.y << 16);
    w.w = __uint_as_float(u.y & 0xffff0000u);
    return w;
}

__device__ __forceinline__ void fma16(float4& a0, float4& a1, float4& a2,
                                      float4& a3, float4 w, float4 xv) {
    a0.x = fmaf(xv.x, w.x, a0.x); a0.y = fmaf(xv.x, w.y, a0.y);
    a0.z = fmaf(xv.x, w.z, a0.z); a0.w = fmaf(xv.x, w.w, a0.w);
    a1.x = fmaf(xv.y, w.x, a1.x); a1.y = fmaf(xv.y, w.y, a1.y);
    a1.z = fmaf(xv.y, w.z, a1.z); a1.w = fmaf(xv.y, w.w, a1.w);
    a2.x = fmaf(xv.z, w.x, a2.x); a2.y = fmaf(xv.z, w.y, a2.y);
    a2.z = fmaf(xv.z, w.z, a2.z); a2.w = fmaf(xv.z, w.w, a2.w);
    a3.x = fmaf(xv.w, w.x, a3.x); a3.y = fmaf(xv.w, w.y, a3.y);
    a3.z = fmaf(xv.w, w.z, a3.z); a3.w = fmaf(xv.w, w.w, a3.w);
}

// ---------------------------------------------------------------------------
// MEGA kernel (round-9 structure + 16-deep W pipeline + GEMM2 K-split):
//   bid <  40  : dense producer (group 255, 250 genes) -> hpartD, ctr++
//   bid 40..294: sparse group g = bid-40, fully fused in-block
//   bid == 295 : dense consumer: spin ctr, reduce 40 partials, fused tail
// GEMM1: waves = (kh K-half) x (bh -> batches 8bh..8bh+7); tc = t&63 spans
//   the full 512B bf16 W-row coalesced; explicit double-buffered 16-gene
//   window keeps 16 loads in flight per wave.
// GEMM2: waves = (kh2 K-half of 256) x (bh2 -> batches 8bh2..8bh2+7); each
//   wave streams only 128 w2t rows (block VMEM 2MB -> 1MB), 32 FMA / 16B.
// ---------------------------------------------------------------------------
__global__ __launch_bounds__(512, 2) void mega_k(const uint2* __restrict__ w1bf,
                                                 const float4* __restrict__ xt4,
                                                 const int* __restrict__ cnt,
                                                 const unsigned short* __restrict__ idx,
                                                 const float4* __restrict__ b1_4,
                                                 const float* __restrict__ g1,
                                                 const float* __restrict__ be1,
                                                 const float4* __restrict__ w2t4,
                                                 const float4* __restrict__ b2_4,
                                                 const float* __restrict__ g2,
                                                 const float* __restrict__ be2,
                                                 float4* __restrict__ hpartD,
                                                 int* __restrict__ ctr,
                                                 float4* __restrict__ z4) {
    // ns/xs (GEMM1 staging) and lh are phase-disjoint: overlay.
    __shared__ __align__(16) char smem[38912];
    __shared__ float rs[8], rss[8];
    int* ns = (int*)smem;                              // 256 ints
    float4 (*xs)[9] = (float4 (*)[9])(smem + 1024);    // 256 x 9 float4 (pad)
    float (*lh)[260] = (float (*)[260])smem;           // 32 x 260 floats

    const int bid = blockIdx.x, t = threadIdx.x;
    const int tc = t & 63;             // float4 column 0..63
    const int w  = t >> 6;             // wave id
    const int kh = w >> 2;             // GEMM1 K half
    const int bh = w & 3;              // GEMM1 batch group (8bh..8bh+7)
    const int tb = w;                  // tail row group: rows 4tb..4tb+3

    const bool producer = (bid < DKB_);
    const bool sparse   = (bid >= DKB_ && bid < DKB_ + 255);
    const int g = sparse ? (bid - DKB_) : 255;

    float4 a0, a1, a2, a3;             // tail registers (4-batch mapping)

    if (producer || sparse) {
        // ---------------- phase A: GEMM1, pipelined ----------------
        float4 b0 = make_float4(0.f, 0.f, 0.f, 0.f), b1v = b0, b2v = b0, b3v = b0;
        float4 b4 = b0, b5 = b0, b6 = b0, b7 = b0;
        int k0 = producer ? bid * DCH_ : 0;
        int kend = producer ? k0 + DCH_ : cnt[g];

        for (int base = k0; base < kend; base += TILE_) {
            int kn = min(TILE_, kend - base);
            __syncthreads();                       // protect ns/xs reuse
            if (t < kn)
                ns[t] = producer ? (base + t)
                                 : (int)idx[(size_t)g * N_ + base + t];
            __syncthreads();
            for (int i = t; i < kn * 8; i += 512)  // cooperative x gather
                xs[i >> 3][i & 7] = xt4[(size_t)ns[i >> 3] * 8 + (i & 7)];
            __syncthreads();

            int half = (kn + 1) >> 1;
            int ks = kh ? half : 0;
            int ke = kh ? kn : half;

            uint2 bufA[WIN_], bufB[WIN_];
#pragma unroll
            for (int j = 0; j < WIN_; ++j) {       // preload window 0
                int k = ks + j;
                if (k < ke) bufA[j] = w1bf[(size_t)ns[k] * 64 + tc];
            }
            for (int w0 = ks; w0 < ke; w0 += 2 * WIN_) {
#pragma unroll
                for (int j = 0; j < WIN_; ++j) {   // load window n+1
                    int k = w0 + WIN_ + j;
                    if (k < ke) bufB[j] = w1bf[(size_t)ns[k] * 64 + tc];
                }
#pragma unroll
                for (int j = 0; j < WIN_; ++j) {   // FMA window n
                    int k = w0 + j;
                    if (k < ke) {
                        float4 wv = bf2f4(bufA[j]);
                        float4 xa = xs[k][2 * bh];
                        float4 xb = xs[k][2 * bh + 1];
                        fma16(b0, b1v, b2v, b3v, wv, xa);
                        fma16(b4, b5, b6, b7, wv, xb);
                    }
                }
#pragma unroll
                for (int j = 0; j < WIN_; ++j) {   // load window n+2
                    int k = w0 + 2 * WIN_ + j;
                    if (k < ke) bufA[j] = w1bf[(size_t)ns[k] * 64 + tc];
                }
#pragma unroll
                for (int j = 0; j < WIN_; ++j) {   // FMA window n+1
                    int k = w0 + WIN_ + j;
                    if (k < ke) {
                        float4 wv = bf2f4(bufB[j]);
                        float4 xa = xs[k][2 * bh];
                        float4 xb = xs[k][2 * bh + 1];
                        fma16(b0, b1v, b2v, b3v, wv, xa);
                        fma16(b4, b5, b6, b7, wv, xb);
                    }
                }
            }
        }
        __syncthreads();                   // xs reads done; lh may overlay

        // ---- merge K halves through lh ----
        if (kh == 1) {
            *(float4*)&lh[8 * bh + 0][4 * tc] = b0;
            *(float4*)&lh[8 * bh + 1][4 * tc] = b1v;
            *(float4*)&lh[8 * bh + 2][4 * tc] = b2v;
            *(float4*)&lh[8 * bh + 3][4 * tc] = b3v;
            *(float4*)&lh[8 * bh + 4][4 * tc] = b4;
            *(float4*)&lh[8 * bh + 5][4 * tc] = b5;
            *(float4*)&lh[8 * bh + 6][4 * tc] = b6;
            *(float4*)&lh[8 * bh + 7][4 * tc] = b7;
        }
        __syncthreads();
        if (kh == 0) {
            float4 m[8] = {b0, b1v, b2v, b3v, b4, b5, b6, b7};
            float4 bb = sparse ? b1_4[tc] : make_float4(0.f, 0.f, 0.f, 0.f);
#pragma unroll
            for (int j = 0; j < 8; ++j) {
                float4 p = *(float4*)&lh[8 * bh + j][4 * tc];
                m[j].x += p.x + bb.x; m[j].y += p.y + bb.y;
                m[j].z += p.z + bb.z; m[j].w += p.w + bb.w;
            }
            if (producer) {
                float4* dst = hpartD + (size_t)bid * 2048;
#pragma unroll
                for (int j = 0; j < 8; ++j)
                    dst[(size_t)(8 * bh + j) * 64 + tc] = m[j];
            } else {
#pragma unroll
                for (int j = 0; j < 8; ++j)
                    *(float4*)&lh[8 * bh + j][4 * tc] = m[j];
            }
        }
        if (producer) {
            __threadfence();
            __syncthreads();
            if (t == 0)
                __hip_atomic_fetch_add(ctr, 1, __ATOMIC_RELEASE,
                                       __HIP_MEMORY_SCOPE_AGENT);
            return;
        }
        __syncthreads();
        // redistribute to 4-batch tail mapping
        a0 = *(float4*)&lh[4 * tb + 0][4 * tc];
        a1 = *(float4*)&lh[4 * tb + 1][4 * tc];
        a2 = *(float4*)&lh[4 * tb + 2][4 * tc];
        a3 = *(float4*)&lh[4 * tb + 3][4 * tc];
    } else {
        // ---------------- dense consumer: reduce 40 partials ----------------
        if (t == 0) {
            while (__hip_atomic_load(ctr, __ATOMIC_ACQUIRE,
                                     __HIP_MEMORY_SCOPE_AGENT) < DKB_)
                __builtin_amdgcn_s_sleep(1);
            __threadfence();
        }
        __syncthreads();
        float4 bb = b1_4[tc];
        a0 = bb; a1 = bb; a2 = bb; a3 = bb;
#pragma unroll 8
        for (int kb = 0; kb < DKB_; ++kb) {
            const float4* pp = hpartD + (size_t)kb * 2048 + (4 * tb) * 64 + tc;
            float4 v0 = pp[0], v1 = pp[64], v2 = pp[128], v3 = pp[192];
            a0.x += v0.x; a0.y += v0.y; a0.z += v0.z; a0.w += v0.w;
            a1.x += v1.x; a1.y += v1.y; a1.z += v1.z; a1.w += v1.w;
            a2.x += v2.x; a2.y += v2.y; a2.z += v2.z; a2.w += v2.w;
            a3.x += v3.x; a3.y += v3.y; a3.z += v3.z; a3.w += v3.w;
        }
    }

    // ---------------- phase B: BN1 stats (from registers) ----------------
    float s = 0.f, ss = 0.f;
    {
        float4 aa[4] = {a0, a1, a2, a3};
#pragma unroll
        for (int j = 0; j < 4; ++j) {
            s  += aa[j].x + aa[j].y + aa[j].z + aa[j].w;
            ss += aa[j].x * aa[j].x + aa[j].y * aa[j].y
                + aa[j].z * aa[j].z + aa[j].w * aa[j].w;
        }
    }
#pragma unroll
    for (int o = 32; o > 0; o >>= 1) { s += __shfl_down(s, o); ss += __shfl_down(ss, o); }
    if (tc == 0) { rs[w] = s; rss[w] = ss; }
    __syncthreads();
    float S = 0.f, SS = 0.f;
#pragma unroll
    for (int j = 0; j < 8; ++j) { S += rs[j]; SS += rss[j]; }
    const float inv = 1.0f / (float)(B_ * HID_);
    float mean = S * inv;
    float var  = SS * inv - mean * mean;       // biased, matches jnp.var
    float sc = g1[g] * rsqrtf(var + EPS_);
    float sh = be1[g] - mean * sc;

    // normalize + ReLU own elements -> lh (same cells read above; barrier'd)
    {
        float4 aa[4] = {a0, a1, a2, a3};
#pragma unroll
        for (int j = 0; j < 4; ++j) {
            float4 v;
            v.x = fmaxf(fmaf(aa[j].x, sc, sh), 0.f);
            v.y = fmaxf(fmaf(aa[j].y, sc, sh), 0.f);
            v.z = fmaxf(fmaf(aa[j].z, sc, sh), 0.f);
            v.w = fmaxf(fmaf(aa[j].w, sc, sh), 0.f);
            *(float4*)&lh[4 * tb + j][4 * tc] = v;
        }
    }
    __syncthreads();

    // ---------------- phase C: GEMM2 (2-way K split) ----------------
    const int kh2 = w >> 2;            // K half of 256
    const int bh2 = w & 3;             // batches 8bh2..8bh2+7
    float4 cc[8];
#pragma unroll
    for (int j = 0; j < 8; ++j) cc[j] = make_float4(0.f, 0.f, 0.f, 0.f);
    const int kbeg = kh2 * 128;
#pragma unroll 8
    for (int k = kbeg; k < kbeg + 128; ++k) {
        float4 wv = w2t4[(size_t)k * 64 + tc];         // 1KB/wave, coalesced
#pragma unroll
        for (int j = 0; j < 8; ++j) {
            float xv = lh[8 * bh2 + j][k];             // LDS broadcast
            cc[j].x = fmaf(xv, wv.x, cc[j].x);
            cc[j].y = fmaf(xv, wv.y, cc[j].y);
            cc[j].z = fmaf(xv, wv.z, cc[j].z);
            cc[j].w = fmaf(xv, wv.w, cc[j].w);
        }
    }
    __syncthreads();                   // all lh k-reads complete
    if (kh2 == 1) {
#pragma unroll
        for (int j = 0; j < 8; ++j)
            *(float4*)&lh[8 * bh2 + j][4 * tc] = cc[j];
    }
    __syncthreads();
    if (kh2 == 0) {
        float4 bb2 = b2_4[tc];
#pragma unroll
        for (int j = 0; j < 8; ++j) {
            float4 p = *(float4*)&lh[8 * bh2 + j][4 * tc];
            p.x += cc[j].x + bb2.x; p.y += cc[j].y + bb2.y;
            p.z += cc[j].z + bb2.z; p.w += cc[j].w + bb2.w;
            *(float4*)&lh[8 * bh2 + j][4 * tc] = p;
        }
    }
    __syncthreads();

    // ---------------- BN2 + ReLU + store (4-batch mapping) ----------------
    float4 cz[4];
#pragma unroll
    for (int j = 0; j < 4; ++j) cz[j] = *(float4*)&lh[4 * tb + j][4 * tc];

    s = 0.f; ss = 0.f;
#pragma unroll
    for (int j = 0; j < 4; ++j) {
        s  += cz[j].x + cz[j].y + cz[j].z + cz[j].w;
        ss += cz[j].x * cz[j].x + cz[j].y * cz[j].y
            + cz[j].z * cz[j].z + cz[j].w * cz[j].w;
    }
#pragma unroll
    for (int o = 32; o > 0; o >>= 1) { s += __shfl_down(s, o); ss += __shfl_down(ss, o); }
    if (tc == 0) { rs[w] = s; rss[w] = ss; }   // safe: prior rs reads barrier'd
    __syncthreads();
    S = 0.f; SS = 0.f;
#pragma unroll
    for (int j = 0; j < 8; ++j) { S += rs[j]; SS += rss[j]; }
    mean = S * inv;
    var  = SS * inv - mean * mean;
    float sc2 = g2[g] * rsqrtf(var + EPS_);
    float sh2 = be2[g] - mean * sc2;

#pragma unroll
    for (int j = 0; j < 4; ++j) {
        int b = 4 * tb + j;
        float4 v;
        v.x = fmaxf(fmaf(cz[j].x, sc2, sh2), 0.f);
        v.y = fmaxf(fmaf(cz[j].y, sc2, sh2), 0.f);
        v.z = fmaxf(fmaf(cz[j].z, sc2, sh2), 0.f);
        v.w = fmaxf(fmaf(cz[j].w, sc2, sh2), 0.f);
        z4[(size_t)(b * G_ + g) * 64 + tc] = v;
    }
}

// ---------------------------------------------------------------------------
extern "C" void kernel_launch(void* const* d_in, const int* in_sizes, int n_in,
                              void* d_out, int out_size, void* d_ws, size_t ws_size,
                              hipStream_t stream) {
    const float* x    = (const float*)d_in[0];
    const float* mask = (const float*)d_in[1];
    const float* W1   = (const float*)d_in[2];
    const float* b1   = (const float*)d_in[3];
    const float* g1   = (const float*)d_in[4];
    const float* be1  = (const float*)d_in[5];
    const float* W2   = (const float*)d_in[6];
    const float* b2   = (const float*)d_in[7];
    const float* g2   = (const float*)d_in[8];
    const float* be2  = (const float*)d_in[9];
    float* out = (float*)d_out;

    char* ws = (char*)d_ws;
    size_t off = 0;
    auto take = [&](size_t bytes) {
        char* p = ws + off;
        off = (off + bytes + 255) & ~(size_t)255;
        return p;
    };
    __hip_bfloat16* w1bf = (__hip_bfloat16*)take((size_t)N_ * HID_ * 2);  // (N, HID) bf16
    float* xt            = (float*)take((size_t)N_ * B_ * 4);             // (N, B)
    float* w2t           = (float*)take((size_t)HID_ * HID_ * 4);         // (HID, Z)
    float* hpartD        = (float*)take((size_t)DKB_ * B_ * HID_ * 4);
    int* cnt             = (int*)take((size_t)G_ * 4);
    unsigned short* idx  = (unsigned short*)take((size_t)G_ * N_ * 2);
    int* ctr             = (int*)take(256);

    prep_k<<<PREP_GRID, 256, 0, stream>>>(W1, x, W2, mask, w1bf, xt, w2t,
                                          cnt, idx, ctr);
    mega_k<<<MEGA_GRID, 512, 0, stream>>>((const uint2*)w1bf, (const float4*)xt,
                                          cnt, idx, (const float4*)b1,
                                          g1, be1,
                                          (const float4*)w2t, (const float4*)b2,
                                          g2, be2,
                                          (float4*)hpartD, ctr, (float4*)out);
}

// Round 11
// 90.429 us; speedup vs baseline: 1.4088x; 1.4088x over previous
//
#include <hip/hip_runtime.h>
#include <hip/hip_bf16.h>

#define B_    32
#define N_    10000
#define G_    256
#define HID_  256
#define EPS_  1e-5f

typedef __attribute__((ext_vector_type(8))) short short8_t;
typedef __attribute__((ext_vector_type(4))) float f32x4;

// prep_k grid segmentation
#define TB_W1  2504            // 313 col-tiles x 8 row-tiles (W1: 256 x 10000)
#define TB_X   313             // x: 32 x 10000
#define NB_W2C 64              // W2 -> bf16 cast (no transpose), 1024 elems/blk
#define NB_CMP 256             // mask compaction, one block per g
#define PREP_GRID (TB_W1 + TB_X + NB_W2C + NB_CMP)   // 3137

#define DKB_  40               // dense-group split-K producer blocks
#define DCH_  250              // genes per dense chunk (40*250 = 10000)
#define MEGA_GRID (DKB_ + 255 + 1)   // 296

// LDS geometry (u16 units)
#define WRP_  258              // WR pitch: 32 gene rows x 258 (516B, odd/2 -> bank-free gathers)
#define XAP_  40               // XA pitch: 32 batch rows x 40 (80B, 16B-aligned)
#define LAP_  264              // LA / lhf pitch (528B / 1056B rows, 16B-aligned)

// ---------------------------------------------------------------------------
// Tiled transpose helpers.
// ---------------------------------------------------------------------------
__device__ inline void transpose_tile(const float* __restrict__ src,
                                      float* __restrict__ dst,
                                      int R, int C, int bx, int by, int t,
                                      float (*tile)[33]) {
    int tx = t & 31, ty = t >> 5;      // 32 x 8
    int c0 = bx * 32, r0 = by * 32;
#pragma unroll
    for (int j = 0; j < 4; ++j) {
        int r = r0 + ty + j * 8, c = c0 + tx;
        if (r < R && c < C) tile[ty + j * 8][tx] = src[(size_t)r * C + c];
    }
    __syncthreads();
#pragma unroll
    for (int j = 0; j < 4; ++j) {
        int c = c0 + ty + j * 8, r = r0 + tx;
        if (r < R && c < C) dst[(size_t)c * R + r] = tile[tx][ty + j * 8];
    }
}

__device__ inline void transpose_tile_bf16(const float* __restrict__ src,
                                           __hip_bfloat16* __restrict__ dst,
                                           int R, int C, int bx, int by, int t,
                                           float (*tile)[33]) {
    int tx = t & 31, ty = t >> 5;      // 32 x 8
    int c0 = bx * 32, r0 = by * 32;
#pragma unroll
    for (int j = 0; j < 4; ++j) {
        int r = r0 + ty + j * 8, c = c0 + tx;
        if (r < R && c < C) tile[ty + j * 8][tx] = src[(size_t)r * C + c];
    }
    __syncthreads();
#pragma unroll
    for (int j = 0; j < 4; ++j) {
        int c = c0 + ty + j * 8, r = r0 + tx;
        if (r < R && c < C)
            dst[(size_t)c * R + r] = __float2bfloat16(tile[tx][ty + j * 8]);
    }
}

// ---------------------------------------------------------------------------
// Fused prep: W1(bf16,NxHID)/x(N,B) transposes + W2 bf16 cast + compaction.
// ---------------------------------------------------------------------------
__global__ __launch_bounds__(256) void prep_k(const float* __restrict__ W1,
                                              const float* __restrict__ x,
                                              const float* __restrict__ W2,
                                              const float* __restrict__ mask,
                                              __hip_bfloat16* __restrict__ w1bf,
                                              float* __restrict__ xt,
                                              __hip_bfloat16* __restrict__ w2bf,
                                              int* __restrict__ cnt,
                                              unsigned short* __restrict__ idx,
                                              int* __restrict__ ctr) {
    __shared__ float tile[32][33];
    __shared__ int c;
    int bid = blockIdx.x, t = threadIdx.x;

    if (bid == 0 && t == 0) *ctr = 0;  // reset mega_k producer counter

    if (bid < TB_W1) {
        transpose_tile_bf16(W1, w1bf, HID_, N_, bid % 313, bid / 313, t, tile);
    } else if (bid < TB_W1 + TB_X) {
        transpose_tile(x, xt, B_, N_, bid - TB_W1, 0, t, tile);
    } else if (bid < TB_W1 + TB_X + NB_W2C) {
        int b = bid - (TB_W1 + TB_X);
#pragma unroll
        for (int j = 0; j < 4; ++j) {
            int i = b * 1024 + j * 256 + t;
            w2bf[i] = __float2bfloat16(W2[i]);
        }
    } else {
        int g = bid - (TB_W1 + TB_X + NB_W2C);
        if (t == 0) c = 0;
        __syncthreads();
        for (int n = t; n < N_; n += 256) {
            if (mask[(size_t)g * N_ + n] != 0.0f) {
                int p = atomicAdd(&c, 1);          // LDS atomic only
                idx[(size_t)g * N_ + p] = (unsigned short)n;
            }
        }
        __syncthreads();
        if (t == 0) cnt[g] = c;
    }
}

// ---------------------------------------------------------------------------
// MEGA kernel, MFMA edition.
//   bid <  40  : dense producer (group 255, 250 genes) -> hpartD (f32), ctr++
//   bid 40..294: sparse group g = bid-40, fully fused in-block
//   bid == 295 : dense consumer: spin ctr, reduce partials, fused tail
// 512 threads = 8 waves. Wave w owns output cols [w*32, w*32+32) (2 N-tiles)
// x both M-tiles (rows 0..31). Fragments (ISA §10, guide §3):
//   A: lane l -> A[l&15][(l>>4)*8+j]   B: lane l -> B[(l>>4)*8+j][l&15]
//   C/D: lane l reg r -> D[(l>>4)*4+r][l&15]
// ---------------------------------------------------------------------------
__global__ __launch_bounds__(512, 2) void mega_k(const unsigned int* __restrict__ w1bfU,
                                                 const float* __restrict__ xtF,
                                                 const int* __restrict__ cnt,
                                                 const unsigned short* __restrict__ idx,
                                                 const float* __restrict__ b1,
                                                 const float* __restrict__ g1,
                                                 const float* __restrict__ be1,
                                                 const unsigned short* __restrict__ w2bf,
                                                 const float* __restrict__ b2,
                                                 const float* __restrict__ g2,
                                                 const float* __restrict__ be2,
                                                 float* __restrict__ hpartD,
                                                 int* __restrict__ ctr,
                                                 float* __restrict__ zout) {
    // Phase-A region (WR+XA+ns, 19.2KB) overlaid by lhf (33.8KB); LA separate.
    __shared__ __align__(16) char smem[50688];
    __shared__ float rs[8], rss[8];
    unsigned short* WR = (unsigned short*)smem;             // [32][258] gene rows
    unsigned short* XA = (unsigned short*)(smem + 16512);   // [32][40]  x bf16
    int* ns            = (int*)(smem + 19072);              // [32]
    float* lhf         = (float*)smem;                      // [32][264] f32
    unsigned short* LA = (unsigned short*)(smem + 33792);   // [32][264] bf16

    const int t = threadIdx.x, bid = blockIdx.x;
    const int w   = t >> 6;            // wave id -> N cols [w*32, w*32+32)
    const int l   = t & 63;
    const int lm  = l & 15;            // intra-tile m/n index
    const int kg  = l >> 4;            // k-group (0..3)
    const int kg8 = kg * 8;

    const bool producer = (bid < DKB_);
    const bool sparse   = (bid >= DKB_ && bid < DKB_ + 255);
    const int g = sparse ? (bid - DKB_) : 255;

    f32x4 acc[2][2];                   // [mt][nt]
#pragma unroll
    for (int mt = 0; mt < 2; ++mt)
#pragma unroll
        for (int nt = 0; nt < 2; ++nt)
#pragma unroll
            for (int r = 0; r < 4; ++r) acc[mt][nt][r] = 0.f;

    if (producer || sparse) {
        // ================= phase A: GEMM1 via MFMA =================
        int k0   = producer ? bid * DCH_ : 0;
        int kend = producer ? k0 + DCH_ : cnt[g];

        for (int base = k0; base < kend; base += 32) {
            int kn = min(32, kend - base);
            __syncthreads();                    // protect WR/XA/ns reuse
            if (t < 32) {
                int nsv = base + t;
                if (!producer && t < kn)
                    nsv = (int)idx[(size_t)g * N_ + base + t];
                ns[t] = nsv;
            }
            __syncthreads();
            // stage WR[k][h]: natural gene-row copy, conflict-free u32 writes
#pragma unroll
            for (int it = 0; it < 8; ++it) {
                int id = it * 512 + t;
                int k = id >> 7, hh = id & 127;
                unsigned int v = (k < kn) ? w1bfU[(size_t)ns[k] * 128 + hh] : 0u;
                *(unsigned int*)&WR[k * WRP_ + 2 * hh] = v;
            }
            // stage XA[b][k]: x gather -> bf16 (zero-pad k >= kn)
#pragma unroll
            for (int it = 0; it < 2; ++it) {
                int id = it * 512 + t;
                int b = id & 31, k = id >> 5;
                float xv = (k < kn) ? xtF[(size_t)ns[k] * 32 + b] : 0.f;
                __hip_bfloat16 hb = __float2bfloat16(xv);
                XA[b * XAP_ + k] = *reinterpret_cast<unsigned short*>(&hb);
            }
            __syncthreads();

            short8_t af[2], bfm[2];
#pragma unroll
            for (int mt = 0; mt < 2; ++mt)
                af[mt] = *(const short8_t*)&XA[(mt * 16 + lm) * XAP_ + kg8];
#pragma unroll
            for (int nt = 0; nt < 2; ++nt) {
                int h = w * 32 + nt * 16 + lm;
                short8_t bq;
#pragma unroll
                for (int j = 0; j < 8; ++j)         // conflict-free u16 gather
                    bq[j] = (short)WR[(kg8 + j) * WRP_ + h];
                bfm[nt] = bq;
            }
#pragma unroll
            for (int mt = 0; mt < 2; ++mt)
#pragma unroll
                for (int nt = 0; nt < 2; ++nt)
                    acc[mt][nt] = __builtin_amdgcn_mfma_f32_16x16x32_bf16(
                        af[mt], bfm[nt], acc[mt][nt], 0, 0, 0);
        }
        __syncthreads();               // WR/XA reads done; lhf may overlay

        if (producer) {
            // accs -> lhf -> coalesced hpartD
#pragma unroll
            for (int mt = 0; mt < 2; ++mt)
#pragma unroll
                for (int nt = 0; nt < 2; ++nt)
#pragma unroll
                    for (int r = 0; r < 4; ++r)
                        lhf[(mt * 16 + kg * 4 + r) * LAP_ +
                            (w * 32 + nt * 16 + lm)] = acc[mt][nt][r];
            __syncthreads();
#pragma unroll
            for (int it = 0; it < 16; ++it) {
                int id = it * 512 + t;
                hpartD[(size_t)bid * 8192 + id] = lhf[(id >> 8) * LAP_ + (id & 255)];
            }
            __threadfence();
            __syncthreads();
            if (t == 0)
                __hip_atomic_fetch_add(ctr, 1, __ATOMIC_RELEASE,
                                       __HIP_MEMORY_SCOPE_AGENT);
            return;
        }

        // -------- sparse: + b1, BN1 stats from registers --------
        float b1v0 = b1[w * 32 + lm], b1v1 = b1[w * 32 + 16 + lm];
        float s = 0.f, ss = 0.f;
#pragma unroll
        for (int mt = 0; mt < 2; ++mt)
#pragma unroll
            for (int nt = 0; nt < 2; ++nt)
#pragma unroll
                for (int r = 0; r < 4; ++r) {
                    float v = acc[mt][nt][r] + (nt ? b1v1 : b1v0);
                    acc[mt][nt][r] = v;
                    s += v; ss += v * v;
                }
#pragma unroll
        for (int o = 32; o > 0; o >>= 1) { s += __shfl_down(s, o); ss += __shfl_down(ss, o); }
        if (l == 0) { rs[w] = s; rss[w] = ss; }
        __syncthreads();
        float S = 0.f, SS = 0.f;
#pragma unroll
        for (int j = 0; j < 8; ++j) { S += rs[j]; SS += rss[j]; }
        const float inv = 1.0f / (float)(B_ * HID_);
        float mean = S * inv;
        float var  = SS * inv - mean * mean;      // biased, matches jnp.var
        float sc = g1[g] * rsqrtf(var + EPS_);
        float sh = be1[g] - mean * sc;
        // normalize + ReLU -> LA (bf16)
#pragma unroll
        for (int mt = 0; mt < 2; ++mt)
#pragma unroll
            for (int nt = 0; nt < 2; ++nt)
#pragma unroll
                for (int r = 0; r < 4; ++r) {
                    float y = fmaxf(fmaf(acc[mt][nt][r], sc, sh), 0.f);
                    __hip_bfloat16 hb = __float2bfloat16(y);
                    LA[(mt * 16 + kg * 4 + r) * LAP_ + (w * 32 + nt * 16 + lm)] =
                        *reinterpret_cast<unsigned short*>(&hb);
                }
        __syncthreads();
    } else {
        // ================= dense consumer =================
        if (t == 0) {
            while (__hip_atomic_load(ctr, __ATOMIC_ACQUIRE,
                                     __HIP_MEMORY_SCOPE_AGENT) < DKB_)
                __builtin_amdgcn_s_sleep(1);
            __threadfence();
        }
        __syncthreads();
        float s = 0.f, ss = 0.f;
#pragma unroll
        for (int it = 0; it < 16; ++it) {
            int id = it * 512 + t;
            float v = b1[id & 255];
            for (int kb = 0; kb < DKB_; ++kb)
                v += hpartD[(size_t)kb * 8192 + id];
            lhf[(id >> 8) * LAP_ + (id & 255)] = v;
            s += v; ss += v * v;
        }
#pragma unroll
        for (int o = 32; o > 0; o >>= 1) { s += __shfl_down(s, o); ss += __shfl_down(ss, o); }
        if (l == 0) { rs[w] = s; rss[w] = ss; }
        __syncthreads();
        float S = 0.f, SS = 0.f;
#pragma unroll
        for (int j = 0; j < 8; ++j) { S += rs[j]; SS += rss[j]; }
        const float inv = 1.0f / (float)(B_ * HID_);
        float mean = S * inv;
        float var  = SS * inv - mean * mean;
        float sc = g1[255] * rsqrtf(var + EPS_);
        float sh = be1[255] - mean * sc;
#pragma unroll
        for (int it = 0; it < 16; ++it) {
            int id = it * 512 + t;
            float v = lhf[(id >> 8) * LAP_ + (id & 255)];
            float y = fmaxf(fmaf(v, sc, sh), 0.f);
            __hip_bfloat16 hb = __float2bfloat16(y);
            LA[(id >> 8) * LAP_ + (id & 255)] =
                *reinterpret_cast<unsigned short*>(&hb);
        }
        __syncthreads();
    }

    // ================= GEMM2 via MFMA + BN2 + ReLU =================
    f32x4 a2[2][2];
#pragma unroll
    for (int mt = 0; mt < 2; ++mt)
#pragma unroll
        for (int nt = 0; nt < 2; ++nt)
#pragma unroll
            for (int r = 0; r < 4; ++r) a2[mt][nt][r] = 0.f;

#pragma unroll
    for (int ks = 0; ks < 8; ++ks) {
        short8_t af[2], bfm[2];
#pragma unroll
        for (int mt = 0; mt < 2; ++mt)
            af[mt] = *(const short8_t*)&LA[(mt * 16 + lm) * LAP_ + ks * 32 + kg8];
#pragma unroll
        for (int nt = 0; nt < 2; ++nt)
            bfm[nt] = *(const short8_t*)&w2bf[(size_t)(w * 32 + nt * 16 + lm) * 256 +
                                              ks * 32 + kg8];
#pragma unroll
        for (int mt = 0; mt < 2; ++mt)
#pragma unroll
            for (int nt = 0; nt < 2; ++nt)
                a2[mt][nt] = __builtin_amdgcn_mfma_f32_16x16x32_bf16(
                    af[mt], bfm[nt], a2[mt][nt], 0, 0, 0);
    }

    float b2v0 = b2[w * 32 + lm], b2v1 = b2[w * 32 + 16 + lm];
    float s2 = 0.f, ss2 = 0.f;
#pragma unroll
    for (int mt = 0; mt < 2; ++mt)
#pragma unroll
        for (int nt = 0; nt < 2; ++nt)
#pragma unroll
            for (int r = 0; r < 4; ++r) {
                float v = a2[mt][nt][r] + (nt ? b2v1 : b2v0);
                a2[mt][nt][r] = v;
                s2 += v; ss2 += v * v;
            }
#pragma unroll
    for (int o = 32; o > 0; o >>= 1) { s2 += __shfl_down(s2, o); ss2 += __shfl_down(ss2, o); }
    if (l == 0) { rs[w] = s2; rss[w] = ss2; }   // safe: prior rs reads barrier'd
    __syncthreads();
    float S2 = 0.f, SS2 = 0.f;
#pragma unroll
    for (int j = 0; j < 8; ++j) { S2 += rs[j]; SS2 += rss[j]; }
    const float inv = 1.0f / (float)(B_ * HID_);
    float mean2 = S2 * inv;
    float var2  = SS2 * inv - mean2 * mean2;
    float sc2 = g2[g] * rsqrtf(var2 + EPS_);
    float sh2 = be2[g] - mean2 * sc2;

#pragma unroll
    for (int mt = 0; mt < 2; ++mt)
#pragma unroll
        for (int nt = 0; nt < 2; ++nt)
#pragma unroll
            for (int r = 0; r < 4; ++r) {
                int b = mt * 16 + kg * 4 + r;
                int z = w * 32 + nt * 16 + lm;
                zout[((size_t)b * G_ + g) * 256 + z] =
                    fmaxf(fmaf(a2[mt][nt][r], sc2, sh2), 0.f);
            }
}

// ---------------------------------------------------------------------------
extern "C" void kernel_launch(void* const* d_in, const int* in_sizes, int n_in,
                              void* d_out, int out_size, void* d_ws, size_t ws_size,
                              hipStream_t stream) {
    const float* x    = (const float*)d_in[0];
    const float* mask = (const float*)d_in[1];
    const float* W1   = (const float*)d_in[2];
    const float* b1   = (const float*)d_in[3];
    const float* g1   = (const float*)d_in[4];
    const float* be1  = (const float*)d_in[5];
    const float* W2   = (const float*)d_in[6];
    const float* b2   = (const float*)d_in[7];
    const float* g2   = (const float*)d_in[8];
    const float* be2  = (const float*)d_in[9];
    float* out = (float*)d_out;

    char* ws = (char*)d_ws;
    size_t off = 0;
    auto take = [&](size_t bytes) {
        char* p = ws + off;
        off = (off + bytes + 255) & ~(size_t)255;
        return p;
    };
    __hip_bfloat16* w1bf = (__hip_bfloat16*)take((size_t)N_ * HID_ * 2);  // (N,HID) bf16
    float* xt            = (float*)take((size_t)N_ * B_ * 4);             // (N,B) f32
    __hip_bfloat16* w2bf = (__hip_bfloat16*)take((size_t)HID_ * HID_ * 2);// (Z,HID) bf16
    float* hpartD        = (float*)take((size_t)DKB_ * B_ * HID_ * 4);
    int* cnt             = (int*)take((size_t)G_ * 4);
    unsigned short* idx  = (unsigned short*)take((size_t)G_ * N_ * 2);
    int* ctr             = (int*)take(256);

    prep_k<<<PREP_GRID, 256, 0, stream>>>(W1, x, W2, mask, w1bf, xt, w2bf,
                                          cnt, idx, ctr);
    mega_k<<<MEGA_GRID, 512, 0, stream>>>((const unsigned int*)w1bf, xt,
                                          cnt, idx, b1, g1, be1,
                                          (const unsigned short*)w2bf,
                                          b2, g2, be2,
                                          hpartD, ctr, out);
}